// Round 2
// baseline (2727.707 us; speedup 1.0000x reference)
//
#include <hip/hip_runtime.h>
#include <hip/hip_bf16.h>

#define NEG_SLOPE 0.2f
using bf16 = __hip_bfloat16;

__device__ __forceinline__ unsigned fkey(float f) {
  unsigned u = __float_as_uint(f);
  return (u & 0x80000000u) ? ~u : (u | 0x80000000u);
}
__device__ __forceinline__ float fdec(unsigned k) {
  return (k & 0x80000000u) ? __uint_as_float(k ^ 0x80000000u) : __uint_as_float(~k);
}

// ---------------- GEMM: h1 = x @ g1_W  (M x 128 @ 128 x 512), fused per-head att dots.
// Output h1 stored as bf16.
__global__ __launch_bounds__(256)
void gemm_h1_kernel(const float* __restrict__ A, const float* __restrict__ B,
                    const float* __restrict__ att_s, const float* __restrict__ att_d,
                    bf16* __restrict__ H1, float* __restrict__ a_src, float* __restrict__ a_dst,
                    int M) {
  __shared__ float As[64][65];
  __shared__ float Bs[64][64];
  const int t = threadIdx.x;
  const int tx = t & 15, ty = t >> 4;
  const int m0 = blockIdx.x * 64;
  const int n0 = blockIdx.y * 64;   // head h = blockIdx.y
  float acc[4][4] = {};
  for (int kk = 0; kk < 128; kk += 64) {
    #pragma unroll
    for (int i = 0; i < 4; i++) {          // A tile 64x64
      int linear = i * 1024 + t * 4;
      int m = linear >> 6, k4 = linear & 63;
      int gm = m0 + m;
      float4 v = make_float4(0.f, 0.f, 0.f, 0.f);
      if (gm < M) v = *reinterpret_cast<const float4*>(&A[gm * 128 + kk + k4]);
      As[m][k4] = v.x; As[m][k4 + 1] = v.y; As[m][k4 + 2] = v.z; As[m][k4 + 3] = v.w;
    }
    #pragma unroll
    for (int i = 0; i < 4; i++) {          // B tile 64x64
      int linear = i * 1024 + t * 4;
      int k = linear >> 6, n4 = linear & 63;
      *reinterpret_cast<float4*>(&Bs[k][n4]) =
          *reinterpret_cast<const float4*>(&B[(kk + k) * 512 + n0 + n4]);
    }
    __syncthreads();
    #pragma unroll 4
    for (int k = 0; k < 64; k++) {
      float4 b = *reinterpret_cast<const float4*>(&Bs[k][tx * 4]);
      float a[4];
      #pragma unroll
      for (int i = 0; i < 4; i++) a[i] = As[ty * 4 + i][k];
      #pragma unroll
      for (int i = 0; i < 4; i++) {
        acc[i][0] += a[i] * b.x; acc[i][1] += a[i] * b.y;
        acc[i][2] += a[i] * b.z; acc[i][3] += a[i] * b.w;
      }
    }
    __syncthreads();
  }
  const int h = blockIdx.y;
  float as4[4], ad4[4];
  #pragma unroll
  for (int j = 0; j < 4; j++) {
    as4[j] = att_s[h * 64 + tx * 4 + j];
    ad4[j] = att_d[h * 64 + tx * 4 + j];
  }
  #pragma unroll
  for (int i = 0; i < 4; i++) {
    int gm = m0 + ty * 4 + i;
    float vs = 0.f, vd = 0.f;
    #pragma unroll
    for (int j = 0; j < 4; j++) { vs += acc[i][j] * as4[j]; vd += acc[i][j] * ad4[j]; }
    #pragma unroll
    for (int m = 1; m < 16; m <<= 1) { vs += __shfl_xor(vs, m); vd += __shfl_xor(vd, m); }
    if (gm < M) {
      if (tx == 0) { a_src[gm * 8 + h] = vs; a_dst[gm * 8 + h] = vd; }
      union { bf16 b[4]; ushort4 u; } pk;
      #pragma unroll
      for (int j = 0; j < 4; j++) pk.b[j] = __float2bfloat16(acc[i][j]);
      *reinterpret_cast<ushort4*>(&H1[gm * 512 + n0 + tx * 4]) = pk.u;
    }
  }
}

// ---------------- CSR build
__global__ void deg_kernel(const int* __restrict__ ei, int* __restrict__ deg, int E, int EP) {
  int e = blockIdx.x * blockDim.x + threadIdx.x;
  if (e >= EP) return;
  int d = (e < E) ? ei[E + e] : (e - E);
  atomicAdd(&deg[d], 1);
}

__global__ __launch_bounds__(1024)
void scan_kernel(const int* __restrict__ deg, int* __restrict__ offs, int n) {
  __shared__ int sums[1024];
  int t = threadIdx.x;
  int chunk = (n + 1023) >> 10;
  int lo = t * chunk, hi = min(lo + chunk, n);
  int s = 0;
  for (int i = lo; i < hi; i++) s += deg[i];
  sums[t] = s;
  __syncthreads();
  for (int step = 1; step < 1024; step <<= 1) {
    int v = (t >= step) ? sums[t - step] : 0;
    __syncthreads();
    sums[t] += v;
    __syncthreads();
  }
  int run = (t == 0) ? 0 : sums[t - 1];
  for (int i = lo; i < hi; i++) { offs[i] = run; run += deg[i]; }
  if (t == 1023) offs[n] = sums[1023];
}

__global__ void scatter_kernel(const int* __restrict__ ei, const int* __restrict__ offs,
                               int* __restrict__ cursor, int* __restrict__ epos,
                               int* __restrict__ esrc, int E, int EP) {
  int e = blockIdx.x * blockDim.x + threadIdx.x;
  if (e >= EP) return;
  int s = (e < E) ? ei[e] : (e - E);
  int d = (e < E) ? ei[E + e] : (e - E);
  int pos = offs[d] + atomicAdd(&cursor[d], 1);
  epos[e] = pos; esrc[pos] = s;
}

// ---------------- edge logits (templated on heads), written in CSR order
template <int H>
__global__ void edge_logits_kernel(const int* __restrict__ ei, const int* __restrict__ epos,
                                   const float* __restrict__ a_src, const float* __restrict__ a_dst,
                                   float* __restrict__ logit, unsigned* __restrict__ maxkey,
                                   int E, int EP) {
  int e = blockIdx.x * blockDim.x + threadIdx.x;
  if (e >= EP) return;
  int s = (e < E) ? ei[e] : (e - E);
  int d = (e < E) ? ei[E + e] : (e - E);
  int pos = epos[e];
  #pragma unroll
  for (int h = 0; h < H; h++) {
    float l = a_src[s * H + h] + a_dst[d * H + h];
    l = (l > 0.f) ? l : NEG_SLOPE * l;
    logit[pos * H + h] = l;
    atomicMax(&maxkey[d * H + h], fkey(l));
  }
}

// ---------------- folded-weight precompute
__global__ void w1p_kernel(const float* __restrict__ sk1_W, const float* __restrict__ g3_W,
                           float* __restrict__ W1p) {
  int i = blockIdx.x * 256 + threadIdx.x;  // < 2048
  int k = i >> 4, j = i & 15;
  float acc = 0.f;
  for (int m = 0; m < 512; m++) acc += sk1_W[k * 512 + m] * g3_W[m * 16 + j];
  W1p[i] = acc;
}
__global__ void w2p_kernel(const float* __restrict__ sk2_W, const float* __restrict__ g3_W,
                           float* __restrict__ W2p) {
  int i = blockIdx.x * 256 + threadIdx.x;  // < 8192
  int k = i >> 4, j = i & 15;
  float acc = 0.f;
  for (int m = 0; m < 512; m++) acc += sk2_W[k * 512 + m] * g3_W[(512 + m) * 16 + j];
  W2p[i] = acc;
}
__global__ void b3p_kernel(const float* __restrict__ sk1_b, const float* __restrict__ sk2_b,
                           const float* __restrict__ g3_W, float* __restrict__ b3p) {
  int j = threadIdx.x;  // 16
  float acc = 0.f;
  for (int m = 0; m < 512; m++)
    acc += sk1_b[m] * g3_W[m * 16 + j] + sk2_b[m] * g3_W[(512 + m) * 16 + j];
  b3p[j] = acc;
}

// ---------------- FUSED: gat1 aggregation + softmax finish + skip-folded h3 + att3 dots.
// One block per node, 512 threads (one per gat1 output channel).
__global__ __launch_bounds__(512)
void agg1_h3_kernel(const int* __restrict__ offs, const int* __restrict__ esrc,
                    const float* __restrict__ p1, const unsigned* __restrict__ maxk1,
                    const bf16* __restrict__ H1, const float* __restrict__ g1_b,
                    const float* __restrict__ X,
                    const float* __restrict__ W1p, const float* __restrict__ W2p,
                    const float* __restrict__ b3p,
                    const float* __restrict__ g3_as, const float* __restrict__ g3_ad,
                    float* __restrict__ H3, float* __restrict__ a3s, float* __restrict__ a3d) {
  __shared__ float x1s[512];
  __shared__ float h3s[16];
  const int n = blockIdx.x;
  const int t = threadIdx.x;
  const int h = t >> 6;
  const float m = fdec(maxk1[n * 8 + h]);
  const int lo = offs[n], hi = offs[n + 1];
  float acc = 0.f, psum = 0.f;
  for (int i = lo; i < hi; i++) {
    float v = __expf(p1[i * 8 + h] - m);
    psum += v;
    acc += v * __bfloat162float(H1[esrc[i] * 512 + t]);
  }
  x1s[t] = acc / (psum + 1e-16f) + g1_b[t];
  __syncthreads();
  // h3[j] = b3p[j] + x[n,:]@W1p[:,j] + x1@W2p[:,j]; 32 threads per j
  const int j = t >> 5, l32 = t & 31;
  float s = 0.f;
  {
    int k = l32 * 4;
    float4 xv = *reinterpret_cast<const float4*>(&X[n * 128 + k]);
    s += xv.x * W1p[k * 16 + j] + xv.y * W1p[(k + 1) * 16 + j] +
         xv.z * W1p[(k + 2) * 16 + j] + xv.w * W1p[(k + 3) * 16 + j];
  }
  #pragma unroll
  for (int c = l32; c < 512; c += 32) s += x1s[c] * W2p[c * 16 + j];
  #pragma unroll
  for (int mm = 1; mm < 32; mm <<= 1) s += __shfl_xor(s, mm);
  if (l32 == 0) h3s[j] = s + b3p[j];
  __syncthreads();
  if (t < 16) {
    float v = h3s[t];
    H3[n * 16 + t] = v;
    float vs = v * g3_as[t], vd = v * g3_ad[t];
    #pragma unroll
    for (int mm = 1; mm < 16; mm <<= 1) { vs += __shfl_xor(vs, mm); vd += __shfl_xor(vd, mm); }
    if (t == 0) { a3s[n] = vs; a3d[n] = vd; }
  }
}

// ---------------- gat3 aggregation (exp + denom folded) -> d_out
__global__ __launch_bounds__(256)
void aggregate3_kernel(const int* __restrict__ offs, const int* __restrict__ esrc,
                       const float* __restrict__ p3, const unsigned* __restrict__ maxk3,
                       const float* __restrict__ H3, const float* __restrict__ g3_b,
                       float* __restrict__ out, int N) {
  int t = threadIdx.x;
  int nl = t >> 4, j = t & 15;
  int n = blockIdx.x * 16 + nl;
  if (n >= N) return;
  float m = fdec(maxk3[n]);
  float acc = 0.f, psum = 0.f;
  int lo = offs[n], hi = offs[n + 1];
  for (int i = lo; i < hi; i++) {
    float v = __expf(p3[i] - m);
    psum += v;
    acc += v * H3[esrc[i] * 16 + j];
  }
  out[n * 16 + j] = acc / (psum + 1e-16f) + g3_b[j];
}

__global__ void sentinel_kernel(float* out) { out[threadIdx.x] = -1e9f; }

extern "C" void kernel_launch(void* const* d_in, const int* in_sizes, int n_in,
                              void* d_out, int out_size, void* d_ws, size_t ws_size,
                              hipStream_t stream) {
  const float* x      = (const float*)d_in[0];
  const int*   ei     = (const int*)d_in[1];
  const float* g1_W   = (const float*)d_in[2];
  const float* g1_as  = (const float*)d_in[3];
  const float* g1_ad  = (const float*)d_in[4];
  const float* g1_b   = (const float*)d_in[5];
  const float* sk1_W  = (const float*)d_in[6];
  const float* sk1_b  = (const float*)d_in[7];
  const float* sk2_W  = (const float*)d_in[8];
  const float* sk2_b  = (const float*)d_in[9];
  const float* g3_W   = (const float*)d_in[10];
  const float* g3_as  = (const float*)d_in[11];
  const float* g3_ad  = (const float*)d_in[12];
  const float* g3_b   = (const float*)d_in[13];
  float* out = (float*)d_out;

  const int N  = in_sizes[0] / 128;
  const int E  = in_sizes[1] / 2;
  const int EP = E + N;

  char* w = (char*)d_ws;
  size_t off = 0;
  auto alloc = [&](size_t bytes) -> void* {
    void* p = w + off;
    off = (off + bytes + 255) & ~(size_t)255;
    return p;
  };

  // zero-init block (single memset)
  int*      deg    = (int*)alloc((size_t)N * 4);
  int*      cursor = (int*)alloc((size_t)N * 4);
  unsigned* maxk1  = (unsigned*)alloc((size_t)N * 8 * 4);
  unsigned* maxk3  = (unsigned*)alloc((size_t)N * 4);
  size_t zbytes = off;
  // rest of workspace
  int*   offs   = (int*)alloc((size_t)(N + 1) * 4);
  int*   esrc   = (int*)alloc((size_t)EP * 4);
  int*   epos   = (int*)alloc((size_t)EP * 4);
  bf16*  h1     = (bf16*)alloc((size_t)N * 512 * 2);
  float* a_src1 = (float*)alloc((size_t)N * 8 * 4);
  float* a_dst1 = (float*)alloc((size_t)N * 8 * 4);
  float* p1     = (float*)alloc((size_t)EP * 8 * 4);
  float* h3     = (float*)alloc((size_t)N * 16 * 4);
  float* a_src3 = (float*)alloc((size_t)N * 4);
  float* a_dst3 = (float*)alloc((size_t)N * 4);
  float* p3     = (float*)alloc((size_t)EP * 4);
  float* W1p    = (float*)alloc(128 * 16 * 4);
  float* W2p    = (float*)alloc(512 * 16 * 4);
  float* b3p    = (float*)alloc(16 * 4);
  (void)n_in; (void)out_size;

  if (off > ws_size) {  // workspace too small: fail loudly but safely
    sentinel_kernel<<<1, 16, 0, stream>>>(out);
    return;
  }

  hipMemsetAsync(d_ws, 0, zbytes, stream);

  int eb = (EP + 255) / 256;

  w1p_kernel<<<8, 256, 0, stream>>>(sk1_W, g3_W, W1p);
  w2p_kernel<<<32, 256, 0, stream>>>(sk2_W, g3_W, W2p);
  b3p_kernel<<<1, 16, 0, stream>>>(sk1_b, sk2_b, g3_W, b3p);

  gemm_h1_kernel<<<dim3((N + 63) / 64, 8), 256, 0, stream>>>(
      x, g1_W, g1_as, g1_ad, h1, a_src1, a_dst1, N);
  deg_kernel<<<eb, 256, 0, stream>>>(ei, deg, E, EP);
  scan_kernel<<<1, 1024, 0, stream>>>(deg, offs, N);
  scatter_kernel<<<eb, 256, 0, stream>>>(ei, offs, cursor, epos, esrc, E, EP);

  edge_logits_kernel<8><<<eb, 256, 0, stream>>>(ei, epos, a_src1, a_dst1, p1, maxk1, E, EP);
  agg1_h3_kernel<<<N, 512, 0, stream>>>(offs, esrc, p1, maxk1, h1, g1_b, x,
                                        W1p, W2p, b3p, g3_as, g3_ad, h3, a_src3, a_dst3);

  edge_logits_kernel<1><<<eb, 256, 0, stream>>>(ei, epos, a_src3, a_dst3, p3, maxk3, E, EP);
  aggregate3_kernel<<<(N + 15) / 16, 256, 0, stream>>>(
      offs, esrc, p3, maxk3, h3, g3_b, out, N);
}

// Round 3
// 1464.384 us; speedup vs baseline: 1.8627x; 1.8627x over previous
//
#include <hip/hip_runtime.h>
#include <hip/hip_bf16.h>

#define NEG_SLOPE 0.2f
using bf16 = __hip_bfloat16;

__device__ __forceinline__ unsigned fkey(float f) {
  unsigned u = __float_as_uint(f);
  return (u & 0x80000000u) ? ~u : (u | 0x80000000u);
}
__device__ __forceinline__ float fdec(unsigned k) {
  return (k & 0x80000000u) ? __uint_as_float(k ^ 0x80000000u) : __uint_as_float(~k);
}
__device__ __forceinline__ float bflo(unsigned u) { return __uint_as_float(u << 16); }
__device__ __forceinline__ float bfhi(unsigned u) { return __uint_as_float(u & 0xffff0000u); }

__device__ __forceinline__ void accum_row(const uint4 r, float v, float acc[8]) {
  acc[0] = fmaf(v, bflo(r.x), acc[0]);
  acc[1] = fmaf(v, bfhi(r.x), acc[1]);
  acc[2] = fmaf(v, bflo(r.y), acc[2]);
  acc[3] = fmaf(v, bfhi(r.y), acc[3]);
  acc[4] = fmaf(v, bflo(r.z), acc[4]);
  acc[5] = fmaf(v, bfhi(r.z), acc[5]);
  acc[6] = fmaf(v, bflo(r.w), acc[6]);
  acc[7] = fmaf(v, bfhi(r.w), acc[7]);
}

// ---------------- GEMM: h1 = x @ g1_W  (M x 128 @ 128 x 512), fused per-head att dots.
__global__ __launch_bounds__(256)
void gemm_h1_kernel(const float* __restrict__ A, const float* __restrict__ B,
                    const float* __restrict__ att_s, const float* __restrict__ att_d,
                    bf16* __restrict__ H1, float* __restrict__ a_src, float* __restrict__ a_dst,
                    int M) {
  __shared__ float As[64][65];
  __shared__ float Bs[64][64];
  const int t = threadIdx.x;
  const int tx = t & 15, ty = t >> 4;
  const int m0 = blockIdx.x * 64;
  const int n0 = blockIdx.y * 64;   // head h = blockIdx.y
  float acc[4][4] = {};
  for (int kk = 0; kk < 128; kk += 64) {
    #pragma unroll
    for (int i = 0; i < 4; i++) {          // A tile 64x64
      int linear = i * 1024 + t * 4;
      int m = linear >> 6, k4 = linear & 63;
      int gm = m0 + m;
      float4 v = make_float4(0.f, 0.f, 0.f, 0.f);
      if (gm < M) v = *reinterpret_cast<const float4*>(&A[gm * 128 + kk + k4]);
      As[m][k4] = v.x; As[m][k4 + 1] = v.y; As[m][k4 + 2] = v.z; As[m][k4 + 3] = v.w;
    }
    #pragma unroll
    for (int i = 0; i < 4; i++) {          // B tile 64x64
      int linear = i * 1024 + t * 4;
      int k = linear >> 6, n4 = linear & 63;
      *reinterpret_cast<float4*>(&Bs[k][n4]) =
          *reinterpret_cast<const float4*>(&B[(kk + k) * 512 + n0 + n4]);
    }
    __syncthreads();
    #pragma unroll 4
    for (int k = 0; k < 64; k++) {
      float4 b = *reinterpret_cast<const float4*>(&Bs[k][tx * 4]);
      float a[4];
      #pragma unroll
      for (int i = 0; i < 4; i++) a[i] = As[ty * 4 + i][k];
      #pragma unroll
      for (int i = 0; i < 4; i++) {
        acc[i][0] += a[i] * b.x; acc[i][1] += a[i] * b.y;
        acc[i][2] += a[i] * b.z; acc[i][3] += a[i] * b.w;
      }
    }
    __syncthreads();
  }
  const int h = blockIdx.y;
  float as4[4], ad4[4];
  #pragma unroll
  for (int j = 0; j < 4; j++) {
    as4[j] = att_s[h * 64 + tx * 4 + j];
    ad4[j] = att_d[h * 64 + tx * 4 + j];
  }
  #pragma unroll
  for (int i = 0; i < 4; i++) {
    int gm = m0 + ty * 4 + i;
    float vs = 0.f, vd = 0.f;
    #pragma unroll
    for (int j = 0; j < 4; j++) { vs += acc[i][j] * as4[j]; vd += acc[i][j] * ad4[j]; }
    #pragma unroll
    for (int m = 1; m < 16; m <<= 1) { vs += __shfl_xor(vs, m); vd += __shfl_xor(vd, m); }
    if (gm < M) {
      if (tx == 0) { a_src[gm * 8 + h] = vs; a_dst[gm * 8 + h] = vd; }
      union { bf16 b[4]; ushort4 u; } pk;
      #pragma unroll
      for (int j = 0; j < 4; j++) pk.b[j] = __float2bfloat16(acc[i][j]);
      *reinterpret_cast<ushort4*>(&H1[gm * 512 + n0 + tx * 4]) = pk.u;
    }
  }
}

// ---------------- CSR build
__global__ void deg_kernel(const int* __restrict__ ei, int* __restrict__ deg, int E, int EP) {
  int e = blockIdx.x * blockDim.x + threadIdx.x;
  if (e >= EP) return;
  int d = (e < E) ? ei[E + e] : (e - E);
  atomicAdd(&deg[d], 1);
}

__global__ __launch_bounds__(1024)
void scan_kernel(const int* __restrict__ deg, int* __restrict__ offs, int n) {
  __shared__ int sums[1024];
  int t = threadIdx.x;
  int chunk = (n + 1023) >> 10;
  int lo = t * chunk, hi = min(lo + chunk, n);
  int s = 0;
  for (int i = lo; i < hi; i++) s += deg[i];
  sums[t] = s;
  __syncthreads();
  for (int step = 1; step < 1024; step <<= 1) {
    int v = (t >= step) ? sums[t - step] : 0;
    __syncthreads();
    sums[t] += v;
    __syncthreads();
  }
  int run = (t == 0) ? 0 : sums[t - 1];
  for (int i = lo; i < hi; i++) { offs[i] = run; run += deg[i]; }
  if (t == 1023) offs[n] = sums[1023];
}

__global__ void scatter_kernel(const int* __restrict__ ei, const int* __restrict__ offs,
                               int* __restrict__ cursor, int* __restrict__ epos,
                               int* __restrict__ esrc, int E, int EP) {
  int e = blockIdx.x * blockDim.x + threadIdx.x;
  if (e >= EP) return;
  int s = (e < E) ? ei[e] : (e - E);
  int d = (e < E) ? ei[E + e] : (e - E);
  int pos = offs[d] + atomicAdd(&cursor[d], 1);
  epos[e] = pos; esrc[pos] = s;
}

// ---------------- edge logits, 8 heads, written TRANSPOSED: p1T[h*EP + pos]
__global__ void edge_logits8_kernel(const int* __restrict__ ei, const int* __restrict__ epos,
                                    const float* __restrict__ a_src, const float* __restrict__ a_dst,
                                    float* __restrict__ p1T, unsigned* __restrict__ maxkey,
                                    int E, int EP) {
  int e = blockIdx.x * blockDim.x + threadIdx.x;
  if (e >= EP) return;
  int s = (e < E) ? ei[e] : (e - E);
  int d = (e < E) ? ei[E + e] : (e - E);
  int pos = epos[e];
  float4 sa = *reinterpret_cast<const float4*>(&a_src[s * 8]);
  float4 sb = *reinterpret_cast<const float4*>(&a_src[s * 8 + 4]);
  float4 da = *reinterpret_cast<const float4*>(&a_dst[d * 8]);
  float4 db = *reinterpret_cast<const float4*>(&a_dst[d * 8 + 4]);
  float lg[8] = { sa.x + da.x, sa.y + da.y, sa.z + da.z, sa.w + da.w,
                  sb.x + db.x, sb.y + db.y, sb.z + db.z, sb.w + db.w };
  #pragma unroll
  for (int h = 0; h < 8; h++) {
    float l = (lg[h] > 0.f) ? lg[h] : NEG_SLOPE * lg[h];
    p1T[(size_t)h * EP + pos] = l;
    atomicMax(&maxkey[d * 8 + h], fkey(l));
  }
}

// ---------------- edge logits, 1 head
__global__ void edge_logits1_kernel(const int* __restrict__ ei, const int* __restrict__ epos,
                                    const float* __restrict__ a_src, const float* __restrict__ a_dst,
                                    float* __restrict__ p3, unsigned* __restrict__ maxkey,
                                    int E, int EP) {
  int e = blockIdx.x * blockDim.x + threadIdx.x;
  if (e >= EP) return;
  int s = (e < E) ? ei[e] : (e - E);
  int d = (e < E) ? ei[E + e] : (e - E);
  float l = a_src[s] + a_dst[d];
  l = (l > 0.f) ? l : NEG_SLOPE * l;
  p3[epos[e]] = l;
  atomicMax(&maxkey[d], fkey(l));
}

// ---------------- folded-weight precompute (TRANSPOSED outputs)
__global__ void w1p_kernel(const float* __restrict__ sk1_W, const float* __restrict__ g3_W,
                           float* __restrict__ W1pT) {
  int i = blockIdx.x * 256 + threadIdx.x;  // < 2048
  int j = i >> 7, k = i & 127;
  float acc = 0.f;
  for (int m = 0; m < 512; m++) acc += sk1_W[k * 512 + m] * g3_W[m * 16 + j];
  W1pT[i] = acc;   // [16][128]
}
__global__ void w2p_kernel(const float* __restrict__ sk2_W, const float* __restrict__ g3_W,
                           float* __restrict__ W2pT) {
  int i = blockIdx.x * 256 + threadIdx.x;  // < 8192
  int j = i >> 9, c = i & 511;
  float acc = 0.f;
  for (int m = 0; m < 512; m++) acc += sk2_W[c * 512 + m] * g3_W[(512 + m) * 16 + j];
  W2pT[i] = acc;   // [16][512]
}
__global__ void b3p_kernel(const float* __restrict__ sk1_b, const float* __restrict__ sk2_b,
                           const float* __restrict__ g3_W, float* __restrict__ b3p) {
  int j = threadIdx.x;  // 16
  float acc = 0.f;
  for (int m = 0; m < 512; m++)
    acc += sk1_b[m] * g3_W[m * 16 + j] + sk2_b[m] * g3_W[(512 + m) * 16 + j];
  b3p[j] = acc;
}

// ---------------- FUSED: gat1 aggregation + softmax + skip-folded h3 + att3 dots.
// ONE WAVE PER NODE; lane l owns channels [8l, 8l+8). 256 threads = 4 nodes/block.
__global__ __launch_bounds__(256)
void agg1_h3_kernel(const int* __restrict__ offs, const int* __restrict__ esrc,
                    const float* __restrict__ p1T, const unsigned* __restrict__ maxk1,
                    const bf16* __restrict__ H1, const float* __restrict__ g1_b,
                    const float* __restrict__ X,
                    const float* __restrict__ W1pT, const float* __restrict__ W2pT,
                    const float* __restrict__ b3p,
                    const float* __restrict__ g3_as, const float* __restrict__ g3_ad,
                    float* __restrict__ H3, float* __restrict__ a3s, float* __restrict__ a3d,
                    int N, int EP) {
  __shared__ float x1s[4][512];
  const int w = threadIdx.x >> 6;
  const int l = threadIdx.x & 63;
  const int n = blockIdx.x * 4 + w;
  if (n >= N) return;                       // no block-level syncs below; per-wave only
  const int h = l >> 3;                     // head of this lane's channel block
  const float m = fdec(maxk1[n * 8 + h]);
  const float* pb = p1T + (size_t)h * EP;
  const uint4* H1v = reinterpret_cast<const uint4*>(H1);
  const int lo = offs[n], hi = offs[n + 1];
  float acc[8] = {0.f, 0.f, 0.f, 0.f, 0.f, 0.f, 0.f, 0.f};
  float psum = 0.f;
  int i = lo;
  for (; i + 4 <= hi; i += 4) {             // 4 rows in flight
    int s0 = esrc[i], s1 = esrc[i + 1], s2 = esrc[i + 2], s3 = esrc[i + 3];
    float q0 = pb[i], q1 = pb[i + 1], q2 = pb[i + 2], q3 = pb[i + 3];
    uint4 r0 = H1v[(size_t)s0 * 64 + l];
    uint4 r1 = H1v[(size_t)s1 * 64 + l];
    uint4 r2 = H1v[(size_t)s2 * 64 + l];
    uint4 r3 = H1v[(size_t)s3 * 64 + l];
    float v0 = __expf(q0 - m), v1 = __expf(q1 - m), v2 = __expf(q2 - m), v3 = __expf(q3 - m);
    psum += v0 + v1 + v2 + v3;
    accum_row(r0, v0, acc); accum_row(r1, v1, acc);
    accum_row(r2, v2, acc); accum_row(r3, v3, acc);
  }
  for (; i < hi; i++) {
    int s = esrc[i];
    float q = pb[i];
    uint4 r = H1v[(size_t)s * 64 + l];
    float v = __expf(q - m);
    psum += v;
    accum_row(r, v, acc);
  }
  const float inv = 1.f / (psum + 1e-16f);
  float4 b0 = *reinterpret_cast<const float4*>(&g1_b[l * 8]);
  float4 b1 = *reinterpret_cast<const float4*>(&g1_b[l * 8 + 4]);
  float4 o0 = make_float4(acc[0] * inv + b0.x, acc[1] * inv + b0.y,
                          acc[2] * inv + b0.z, acc[3] * inv + b0.w);
  float4 o1 = make_float4(acc[4] * inv + b1.x, acc[5] * inv + b1.y,
                          acc[6] * inv + b1.z, acc[7] * inv + b1.w);
  *reinterpret_cast<float4*>(&x1s[w][l * 8]) = o0;
  *reinterpret_cast<float4*>(&x1s[w][l * 8 + 4]) = o1;
  // ---- h3[j] = b3p[j] + x[n]@W1pT[j] + x1@W2pT[j];  j = l>>2, 4 lanes per j
  const int j = l >> 2, sub = l & 3;
  float s = 0.f;
  {
    const float* xr = &X[(size_t)n * 128 + sub * 32];
    const float* wr = &W1pT[j * 128 + sub * 32];
    #pragma unroll
    for (int q = 0; q < 32; q += 4) {
      float4 a = *reinterpret_cast<const float4*>(&xr[q]);
      float4 b = *reinterpret_cast<const float4*>(&wr[q]);
      s += a.x * b.x + a.y * b.y + a.z * b.z + a.w * b.w;
    }
  }
  {
    const float* xr = &x1s[w][sub * 128];
    const float* wr = &W2pT[j * 512 + sub * 128];
    #pragma unroll
    for (int q = 0; q < 128; q += 4) {
      float4 a = *reinterpret_cast<const float4*>(&xr[q]);
      float4 b = *reinterpret_cast<const float4*>(&wr[q]);
      s += a.x * b.x + a.y * b.y + a.z * b.z + a.w * b.w;
    }
  }
  s += __shfl_xor(s, 1);
  s += __shfl_xor(s, 2);
  float v = s + b3p[j];
  float vs = v * g3_as[j], vd = v * g3_ad[j];
  if (sub == 0) H3[(size_t)n * 16 + j] = v;
  else { vs = 0.f; vd = 0.f; }
  #pragma unroll
  for (int mm = 4; mm < 64; mm <<= 1) { vs += __shfl_xor(vs, mm); vd += __shfl_xor(vd, mm); }
  if (l == 0) { a3s[n] = vs; a3d[n] = vd; }
}

// ---------------- gat3 aggregation -> d_out. One wave per node, 4 lane-groups x 16 ch.
__global__ __launch_bounds__(256)
void agg3_kernel(const int* __restrict__ offs, const int* __restrict__ esrc,
                 const float* __restrict__ p3, const unsigned* __restrict__ maxk3,
                 const float* __restrict__ H3, const float* __restrict__ g3_b,
                 float* __restrict__ out, int N) {
  const int w = threadIdx.x >> 6;
  const int l = threadIdx.x & 63;
  const int n = blockIdx.x * 4 + w;
  if (n >= N) return;
  const int g = l >> 4, j = l & 15;
  const float m = fdec(maxk3[n]);
  const int lo = offs[n], hi = offs[n + 1];
  float acc = 0.f, psum = 0.f;
  for (int i = lo + g; i < hi; i += 4) {
    int s = esrc[i];
    float v = __expf(p3[i] - m);
    psum += v;
    acc = fmaf(v, H3[(size_t)s * 16 + j], acc);
  }
  acc += __shfl_xor(acc, 16);  acc += __shfl_xor(acc, 32);
  psum += __shfl_xor(psum, 16); psum += __shfl_xor(psum, 32);
  if (l < 16) out[(size_t)n * 16 + j] = acc / (psum + 1e-16f) + g3_b[j];
}

__global__ void sentinel_kernel(float* out) { out[threadIdx.x] = -1e9f; }

extern "C" void kernel_launch(void* const* d_in, const int* in_sizes, int n_in,
                              void* d_out, int out_size, void* d_ws, size_t ws_size,
                              hipStream_t stream) {
  const float* x      = (const float*)d_in[0];
  const int*   ei     = (const int*)d_in[1];
  const float* g1_W   = (const float*)d_in[2];
  const float* g1_as  = (const float*)d_in[3];
  const float* g1_ad  = (const float*)d_in[4];
  const float* g1_b   = (const float*)d_in[5];
  const float* sk1_W  = (const float*)d_in[6];
  const float* sk1_b  = (const float*)d_in[7];
  const float* sk2_W  = (const float*)d_in[8];
  const float* sk2_b  = (const float*)d_in[9];
  const float* g3_W   = (const float*)d_in[10];
  const float* g3_as  = (const float*)d_in[11];
  const float* g3_ad  = (const float*)d_in[12];
  const float* g3_b   = (const float*)d_in[13];
  float* out = (float*)d_out;

  const int N  = in_sizes[0] / 128;
  const int E  = in_sizes[1] / 2;
  const int EP = E + N;

  char* w = (char*)d_ws;
  size_t off = 0;
  auto alloc = [&](size_t bytes) -> void* {
    void* p = w + off;
    off = (off + bytes + 255) & ~(size_t)255;
    return p;
  };

  // zero-init block (single memset)
  int*      deg    = (int*)alloc((size_t)N * 4);
  int*      cursor = (int*)alloc((size_t)N * 4);
  unsigned* maxk1  = (unsigned*)alloc((size_t)N * 8 * 4);
  unsigned* maxk3  = (unsigned*)alloc((size_t)N * 4);
  size_t zbytes = off;
  // rest of workspace
  int*   offs   = (int*)alloc((size_t)(N + 1) * 4);
  int*   esrc   = (int*)alloc((size_t)EP * 4);
  int*   epos   = (int*)alloc((size_t)EP * 4);
  bf16*  h1     = (bf16*)alloc((size_t)N * 512 * 2);
  float* a_src1 = (float*)alloc((size_t)N * 8 * 4);
  float* a_dst1 = (float*)alloc((size_t)N * 8 * 4);
  float* p1T    = (float*)alloc((size_t)EP * 8 * 4);
  float* h3     = (float*)alloc((size_t)N * 16 * 4);
  float* a_src3 = (float*)alloc((size_t)N * 4);
  float* a_dst3 = (float*)alloc((size_t)N * 4);
  float* W1pT   = (float*)alloc(128 * 16 * 4);
  float* W2pT   = (float*)alloc(512 * 16 * 4);
  float* b3p    = (float*)alloc(16 * 4);
  float* p3     = p1T;   // alias: p1T is dead before edge_logits1 runs
  (void)n_in; (void)out_size;

  if (off > ws_size) {  // workspace too small: fail loudly but safely
    sentinel_kernel<<<1, 16, 0, stream>>>(out);
    return;
  }

  hipMemsetAsync(d_ws, 0, zbytes, stream);

  int eb = (EP + 255) / 256;
  int nb4 = (N + 3) / 4;

  w1p_kernel<<<8, 256, 0, stream>>>(sk1_W, g3_W, W1pT);
  w2p_kernel<<<32, 256, 0, stream>>>(sk2_W, g3_W, W2pT);
  b3p_kernel<<<1, 16, 0, stream>>>(sk1_b, sk2_b, g3_W, b3p);

  gemm_h1_kernel<<<dim3((N + 63) / 64, 8), 256, 0, stream>>>(
      x, g1_W, g1_as, g1_ad, h1, a_src1, a_dst1, N);
  deg_kernel<<<eb, 256, 0, stream>>>(ei, deg, E, EP);
  scan_kernel<<<1, 1024, 0, stream>>>(deg, offs, N);
  scatter_kernel<<<eb, 256, 0, stream>>>(ei, offs, cursor, epos, esrc, E, EP);

  edge_logits8_kernel<<<eb, 256, 0, stream>>>(ei, epos, a_src1, a_dst1, p1T, maxk1, E, EP);
  agg1_h3_kernel<<<nb4, 256, 0, stream>>>(offs, esrc, p1T, maxk1, h1, g1_b, x,
                                          W1pT, W2pT, b3p, g3_as, g3_ad,
                                          h3, a_src3, a_dst3, N, EP);

  edge_logits1_kernel<<<eb, 256, 0, stream>>>(ei, epos, a_src3, a_dst3, p3, maxk3, E, EP);
  agg3_kernel<<<nb4, 256, 0, stream>>>(offs, esrc, p3, maxk3, h3, g3_b, out, N);
}

// Round 4
// 709.849 us; speedup vs baseline: 3.8427x; 2.0630x over previous
//
#include <hip/hip_runtime.h>
#include <hip/hip_bf16.h>

#define NEG_SLOPE 0.2f
using bf16 = __hip_bfloat16;

typedef __attribute__((ext_vector_type(8))) short short8;   // 8 bf16 (4 VGPRs)
typedef __attribute__((ext_vector_type(4))) float f32x4;
#define MFMA16(a, b, c) __builtin_amdgcn_mfma_f32_16x16x32_bf16(a, b, c, 0, 0, 0)

__device__ __forceinline__ float bflo(unsigned u) { return __uint_as_float(u << 16); }
__device__ __forceinline__ float bfhi(unsigned u) { return __uint_as_float(u & 0xffff0000u); }

__device__ __forceinline__ float edge_w(float q, float adh) {
  float t = q + adh;
  t = (t > 0.f) ? t : NEG_SLOPE * t;
  return __expf(t);
}

__device__ __forceinline__ void accum_row(const uint4 r, float v, float (&acc)[8]) {
  acc[0] = fmaf(v, bflo(r.x), acc[0]);
  acc[1] = fmaf(v, bfhi(r.x), acc[1]);
  acc[2] = fmaf(v, bflo(r.y), acc[2]);
  acc[3] = fmaf(v, bfhi(r.y), acc[3]);
  acc[4] = fmaf(v, bflo(r.z), acc[4]);
  acc[5] = fmaf(v, bfhi(r.z), acc[5]);
  acc[6] = fmaf(v, bflo(r.w), acc[6]);
  acc[7] = fmaf(v, bfhi(r.w), acc[7]);
}

// ---------------- casts
__global__ void cast_x_kernel(const float* __restrict__ x, bf16* __restrict__ xb, int total4) {
  int idx = blockIdx.x * blockDim.x + threadIdx.x;
  int stride = gridDim.x * blockDim.x;
  for (int i = idx; i < total4; i += stride) {
    float4 v = reinterpret_cast<const float4*>(x)[i];
    union { bf16 b[4]; ushort4 u; } pk;
    pk.b[0] = __float2bfloat16(v.x); pk.b[1] = __float2bfloat16(v.y);
    pk.b[2] = __float2bfloat16(v.z); pk.b[3] = __float2bfloat16(v.w);
    reinterpret_cast<ushort4*>(xb)[i] = pk.u;
  }
}

// Wt[col][k] = bf16(g1_W[k][col]), col<512, k<128
__global__ void cast_wt_kernel(const float* __restrict__ Wf, bf16* __restrict__ Wt) {
  int i = blockIdx.x * 256 + threadIdx.x;   // < 65536
  int c = i >> 7, k = i & 127;
  Wt[i] = __float2bfloat16(Wf[k * 512 + c]);
}

// ---------------- MFMA GEMM: h1 = xb @ Wt^T  (M x 128 @ 128 x 512) + fused att dots.
// Block 256 thr = 4 waves (2M x 2N). Block tile 64M x 128N. Wave tile 32M x 64N = 1 head.
__global__ __launch_bounds__(256)
void gemm_h1_kernel(const bf16* __restrict__ xb, const bf16* __restrict__ Wt,
                    const float* __restrict__ att_s, const float* __restrict__ att_d,
                    bf16* __restrict__ H1, float* __restrict__ a_src, float* __restrict__ a_dst,
                    int M) {
  const int t = threadIdx.x;
  const int w = t >> 6, l = t & 63;
  const int wm = w & 1, wn = w >> 1;
  const int m0 = blockIdx.x * 64 + wm * 32;
  const int n0 = blockIdx.y * 128 + wn * 64;
  const int head = n0 >> 6;
  const int lr = l & 15, lk = l >> 4;
  const int arow0 = min(m0 + lr, M - 1);
  const int arow1 = min(m0 + 16 + lr, M - 1);
  const bf16* a0p = xb + (size_t)arow0 * 128 + lk * 8;
  const bf16* a1p = xb + (size_t)arow1 * 128 + lk * 8;
  const bf16* bp  = Wt + (size_t)(n0 + lr) * 128 + lk * 8;
  f32x4 acc[2][4] = {};
  #pragma unroll
  for (int kc = 0; kc < 4; kc++) {
    short8 av0 = *reinterpret_cast<const short8*>(a0p + kc * 32);
    short8 av1 = *reinterpret_cast<const short8*>(a1p + kc * 32);
    short8 bv0 = *reinterpret_cast<const short8*>(bp + 0 * 2048 + kc * 32);
    short8 bv1 = *reinterpret_cast<const short8*>(bp + 1 * 2048 + kc * 32);
    short8 bv2 = *reinterpret_cast<const short8*>(bp + 2 * 2048 + kc * 32);
    short8 bv3 = *reinterpret_cast<const short8*>(bp + 3 * 2048 + kc * 32);
    acc[0][0] = MFMA16(av0, bv0, acc[0][0]);
    acc[0][1] = MFMA16(av0, bv1, acc[0][1]);
    acc[0][2] = MFMA16(av0, bv2, acc[0][2]);
    acc[0][3] = MFMA16(av0, bv3, acc[0][3]);
    acc[1][0] = MFMA16(av1, bv0, acc[1][0]);
    acc[1][1] = MFMA16(av1, bv1, acc[1][1]);
    acc[1][2] = MFMA16(av1, bv2, acc[1][2]);
    acc[1][3] = MFMA16(av1, bv3, acc[1][3]);
  }
  float as_r[4], ad_r[4];
  #pragma unroll
  for (int ni = 0; ni < 4; ni++) {
    as_r[ni] = att_s[head * 64 + ni * 16 + lr];
    ad_r[ni] = att_d[head * 64 + ni * 16 + lr];
  }
  #pragma unroll
  for (int mi = 0; mi < 2; mi++) {
    #pragma unroll
    for (int r = 0; r < 4; r++) {
      int row = m0 + mi * 16 + lk * 4 + r;
      bool ok = row < M;
      float vs = 0.f, vd = 0.f;
      #pragma unroll
      for (int ni = 0; ni < 4; ni++) {
        float v = acc[mi][ni][r];
        vs += v * as_r[ni]; vd += v * ad_r[ni];
        if (ok) H1[(size_t)row * 512 + n0 + ni * 16 + lr] = __float2bfloat16(v);
      }
      vs += __shfl_xor(vs, 1); vs += __shfl_xor(vs, 2);
      vs += __shfl_xor(vs, 4); vs += __shfl_xor(vs, 8);
      vd += __shfl_xor(vd, 1); vd += __shfl_xor(vd, 2);
      vd += __shfl_xor(vd, 4); vd += __shfl_xor(vd, 8);
      if (ok && lr == 0) {
        a_src[(size_t)row * 8 + head] = vs;
        a_dst[(size_t)row * 8 + head] = vd;
      }
    }
  }
}

// ---------------- CSR build
__global__ void deg_kernel(const int* __restrict__ ei, int* __restrict__ deg, int E, int EP) {
  int e = blockIdx.x * blockDim.x + threadIdx.x;
  if (e >= EP) return;
  int d = (e < E) ? ei[E + e] : (e - E);
  atomicAdd(&deg[d], 1);
}

__global__ __launch_bounds__(1024)
void scan_kernel(const int* __restrict__ deg, int* __restrict__ offs, int n) {
  __shared__ int sums[1024];
  int t = threadIdx.x;
  int chunk = (n + 1023) >> 10;
  int lo = t * chunk, hi = min(lo + chunk, n);
  int s = 0;
  for (int i = lo; i < hi; i++) s += deg[i];
  sums[t] = s;
  __syncthreads();
  for (int step = 1; step < 1024; step <<= 1) {
    int v = (t >= step) ? sums[t - step] : 0;
    __syncthreads();
    sums[t] += v;
    __syncthreads();
  }
  int run = (t == 0) ? 0 : sums[t - 1];
  for (int i = lo; i < hi; i++) { offs[i] = run; run += deg[i]; }
  if (t == 1023) offs[n] = sums[1023];
}

__global__ void scatter_kernel(const int* __restrict__ ei, const int* __restrict__ offs,
                               int* __restrict__ cursor, int* __restrict__ esrc, int E, int EP) {
  int e = blockIdx.x * blockDim.x + threadIdx.x;
  if (e >= EP) return;
  int s = (e < E) ? ei[e] : (e - E);
  int d = (e < E) ? ei[E + e] : (e - E);
  int pos = offs[d] + atomicAdd(&cursor[d], 1);
  esrc[pos] = s;
}

// ---------------- folded-weight precompute (TRANSPOSED outputs)
__global__ void w1p_kernel(const float* __restrict__ sk1_W, const float* __restrict__ g3_W,
                           float* __restrict__ W1pT) {
  int i = blockIdx.x * 256 + threadIdx.x;  // < 2048
  int j = i >> 7, k = i & 127;
  float acc = 0.f;
  for (int m = 0; m < 512; m++) acc += sk1_W[k * 512 + m] * g3_W[m * 16 + j];
  W1pT[i] = acc;   // [16][128]
}
__global__ void w2p_kernel(const float* __restrict__ sk2_W, const float* __restrict__ g3_W,
                           float* __restrict__ W2pT) {
  int i = blockIdx.x * 256 + threadIdx.x;  // < 8192
  int j = i >> 9, c = i & 511;
  float acc = 0.f;
  for (int m = 0; m < 512; m++) acc += sk2_W[c * 512 + m] * g3_W[(512 + m) * 16 + j];
  W2pT[i] = acc;   // [16][512]
}
__global__ void b3p_kernel(const float* __restrict__ sk1_b, const float* __restrict__ sk2_b,
                           const float* __restrict__ g3_W, float* __restrict__ b3p) {
  int j = threadIdx.x;  // 16
  float acc = 0.f;
  for (int m = 0; m < 512; m++)
    acc += sk1_b[m] * g3_W[m * 16 + j] + sk2_b[m] * g3_W[(512 + m) * 16 + j];
  b3p[j] = acc;
}

// ---------------- FUSED: gat1 softmax-aggregation (logits inline, no max pass) +
// skip-folded h3 GEMV in registers + att3 dots. One wave per node; lane l owns
// channels [8l, 8l+8). No LDS.
__global__ __launch_bounds__(256)
void agg1_h3_kernel(const int* __restrict__ offs, const int* __restrict__ esrc,
                    const float* __restrict__ a_src1, const float* __restrict__ a_dst1,
                    const bf16* __restrict__ H1, const float* __restrict__ g1_b,
                    const float* __restrict__ X,
                    const float* __restrict__ W1pT, const float* __restrict__ W2pT,
                    const float* __restrict__ b3p,
                    const float* __restrict__ g3_as, const float* __restrict__ g3_ad,
                    float* __restrict__ H3, float* __restrict__ a3s, float* __restrict__ a3d,
                    int N) {
  const int l = threadIdx.x & 63;
  const int n = blockIdx.x * 4 + (threadIdx.x >> 6);
  if (n >= N) return;
  const int h = l >> 3;
  const float adh = a_dst1[n * 8 + h];
  const uint4* __restrict__ H1v = reinterpret_cast<const uint4*>(H1);
  const int lo = offs[n], hi = offs[n + 1];
  float acc[8] = {0.f, 0.f, 0.f, 0.f, 0.f, 0.f, 0.f, 0.f};
  float psum = 0.f;
  int i = lo;
  for (; i + 8 <= hi; i += 8) {          // 8 rows in flight
    int s0 = esrc[i+0], s1 = esrc[i+1], s2 = esrc[i+2], s3 = esrc[i+3];
    int s4 = esrc[i+4], s5 = esrc[i+5], s6 = esrc[i+6], s7 = esrc[i+7];
    float q0 = a_src1[s0*8+h], q1 = a_src1[s1*8+h], q2 = a_src1[s2*8+h], q3 = a_src1[s3*8+h];
    float q4 = a_src1[s4*8+h], q5 = a_src1[s5*8+h], q6 = a_src1[s6*8+h], q7 = a_src1[s7*8+h];
    uint4 r0 = H1v[(size_t)s0*64+l], r1 = H1v[(size_t)s1*64+l];
    uint4 r2 = H1v[(size_t)s2*64+l], r3 = H1v[(size_t)s3*64+l];
    uint4 r4 = H1v[(size_t)s4*64+l], r5 = H1v[(size_t)s5*64+l];
    uint4 r6 = H1v[(size_t)s6*64+l], r7 = H1v[(size_t)s7*64+l];
    float v0 = edge_w(q0, adh), v1 = edge_w(q1, adh), v2 = edge_w(q2, adh), v3 = edge_w(q3, adh);
    float v4 = edge_w(q4, adh), v5 = edge_w(q5, adh), v6 = edge_w(q6, adh), v7 = edge_w(q7, adh);
    psum += (v0 + v1 + v2 + v3) + (v4 + v5 + v6 + v7);
    accum_row(r0, v0, acc); accum_row(r1, v1, acc);
    accum_row(r2, v2, acc); accum_row(r3, v3, acc);
    accum_row(r4, v4, acc); accum_row(r5, v5, acc);
    accum_row(r6, v6, acc); accum_row(r7, v7, acc);
  }
  if (i + 4 <= hi) {
    int s0 = esrc[i+0], s1 = esrc[i+1], s2 = esrc[i+2], s3 = esrc[i+3];
    float q0 = a_src1[s0*8+h], q1 = a_src1[s1*8+h], q2 = a_src1[s2*8+h], q3 = a_src1[s3*8+h];
    uint4 r0 = H1v[(size_t)s0*64+l], r1 = H1v[(size_t)s1*64+l];
    uint4 r2 = H1v[(size_t)s2*64+l], r3 = H1v[(size_t)s3*64+l];
    float v0 = edge_w(q0, adh), v1 = edge_w(q1, adh), v2 = edge_w(q2, adh), v3 = edge_w(q3, adh);
    psum += v0 + v1 + v2 + v3;
    accum_row(r0, v0, acc); accum_row(r1, v1, acc);
    accum_row(r2, v2, acc); accum_row(r3, v3, acc);
    i += 4;
  }
  for (; i < hi; i++) {
    int s = esrc[i];
    float q = a_src1[(size_t)s*8+h];
    uint4 r = H1v[(size_t)s*64+l];
    float v = edge_w(q, adh);
    psum += v;
    accum_row(r, v, acc);
  }
  const float inv = 1.f / (psum + 1e-16f);
  float4 ba = *reinterpret_cast<const float4*>(&g1_b[l * 8]);
  float4 bb = *reinterpret_cast<const float4*>(&g1_b[l * 8 + 4]);
  float x1v[8];
  x1v[0] = acc[0]*inv + ba.x; x1v[1] = acc[1]*inv + ba.y;
  x1v[2] = acc[2]*inv + ba.z; x1v[3] = acc[3]*inv + ba.w;
  x1v[4] = acc[4]*inv + bb.x; x1v[5] = acc[5]*inv + bb.y;
  x1v[6] = acc[6]*inv + bb.z; x1v[7] = acc[7]*inv + bb.w;
  float2 xv = *reinterpret_cast<const float2*>(&X[(size_t)n * 128 + l * 2]);
  float p[16];
  #pragma unroll
  for (int j = 0; j < 16; j++) {
    float4 wa = *reinterpret_cast<const float4*>(&W2pT[j * 512 + l * 8]);
    float4 wb = *reinterpret_cast<const float4*>(&W2pT[j * 512 + l * 8 + 4]);
    float2 w1 = *reinterpret_cast<const float2*>(&W1pT[j * 128 + l * 2]);
    p[j] = x1v[0]*wa.x + x1v[1]*wa.y + x1v[2]*wa.z + x1v[3]*wa.w
         + x1v[4]*wb.x + x1v[5]*wb.y + x1v[6]*wb.z + x1v[7]*wb.w
         + xv.x*w1.x + xv.y*w1.y;
  }
  #pragma unroll
  for (int j = 0; j < 16; j++) {
    p[j] += __shfl_xor(p[j], 1);
    p[j] += __shfl_xor(p[j], 2);
    p[j] += __shfl_xor(p[j], 4);
    p[j] += __shfl_xor(p[j], 8);
    p[j] += __shfl_xor(p[j], 16);
    p[j] += __shfl_xor(p[j], 32);
  }
  if (l == 0) {
    float o[16];
    #pragma unroll
    for (int j = 0; j < 16; j++) o[j] = p[j] + b3p[j];
    float4* H3v = reinterpret_cast<float4*>(&H3[(size_t)n * 16]);
    H3v[0] = make_float4(o[0], o[1], o[2], o[3]);
    H3v[1] = make_float4(o[4], o[5], o[6], o[7]);
    H3v[2] = make_float4(o[8], o[9], o[10], o[11]);
    H3v[3] = make_float4(o[12], o[13], o[14], o[15]);
    float vs = 0.f, vd = 0.f;
    #pragma unroll
    for (int j = 0; j < 16; j++) { vs += o[j] * g3_as[j]; vd += o[j] * g3_ad[j]; }
    a3s[n] = vs; a3d[n] = vd;
  }
}

// ---------------- gat3 aggregation (logits inline) -> d_out. Wave/node, 4 groups x 16 ch.
__global__ __launch_bounds__(256)
void agg3_kernel(const int* __restrict__ offs, const int* __restrict__ esrc,
                 const float* __restrict__ a3s, const float* __restrict__ a3d,
                 const float* __restrict__ H3, const float* __restrict__ g3_b,
                 float* __restrict__ out, int N) {
  const int l = threadIdx.x & 63;
  const int n = blockIdx.x * 4 + (threadIdx.x >> 6);
  if (n >= N) return;
  const int g = l >> 4, j = l & 15;
  const float ad = a3d[n];
  const int lo = offs[n], hi = offs[n + 1];
  float acc = 0.f, psum = 0.f;
  int i = lo + g;
  for (; i + 4 < hi; i += 8) {
    int s0 = esrc[i], s1 = esrc[i + 4];
    float q0 = a3s[s0], q1 = a3s[s1];
    float h0 = H3[(size_t)s0 * 16 + j], h1v = H3[(size_t)s1 * 16 + j];
    float v0 = edge_w(q0, ad), v1 = edge_w(q1, ad);
    psum += v0 + v1;
    acc = fmaf(v0, h0, acc);
    acc = fmaf(v1, h1v, acc);
  }
  for (; i < hi; i += 4) {
    int s = esrc[i];
    float v = edge_w(a3s[s], ad);
    psum += v;
    acc = fmaf(v, H3[(size_t)s * 16 + j], acc);
  }
  acc += __shfl_xor(acc, 16);  acc += __shfl_xor(acc, 32);
  psum += __shfl_xor(psum, 16); psum += __shfl_xor(psum, 32);
  if (l < 16) out[(size_t)n * 16 + j] = acc / (psum + 1e-16f) + g3_b[j];
}

__global__ void sentinel_kernel(float* out) { out[threadIdx.x] = -1e9f; }

extern "C" void kernel_launch(void* const* d_in, const int* in_sizes, int n_in,
                              void* d_out, int out_size, void* d_ws, size_t ws_size,
                              hipStream_t stream) {
  const float* x      = (const float*)d_in[0];
  const int*   ei     = (const int*)d_in[1];
  const float* g1_W   = (const float*)d_in[2];
  const float* g1_as  = (const float*)d_in[3];
  const float* g1_ad  = (const float*)d_in[4];
  const float* g1_b   = (const float*)d_in[5];
  const float* sk1_W  = (const float*)d_in[6];
  const float* sk1_b  = (const float*)d_in[7];
  const float* sk2_W  = (const float*)d_in[8];
  const float* sk2_b  = (const float*)d_in[9];
  const float* g3_W   = (const float*)d_in[10];
  const float* g3_as  = (const float*)d_in[11];
  const float* g3_ad  = (const float*)d_in[12];
  const float* g3_b   = (const float*)d_in[13];
  float* out = (float*)d_out;

  const int N  = in_sizes[0] / 128;
  const int E  = in_sizes[1] / 2;
  const int EP = E + N;

  char* w = (char*)d_ws;
  size_t off = 0;
  auto alloc = [&](size_t bytes) -> void* {
    void* p = w + off;
    off = (off + bytes + 255) & ~(size_t)255;
    return p;
  };

  // zero-init block (single memset)
  int* deg    = (int*)alloc((size_t)N * 4);
  int* cursor = (int*)alloc((size_t)N * 4);
  size_t zbytes = off;
  // rest of workspace
  int*   offs   = (int*)alloc((size_t)(N + 1) * 4);
  int*   esrc   = (int*)alloc((size_t)EP * 4);
  bf16*  xb     = (bf16*)alloc((size_t)N * 128 * 2);
  bf16*  Wt     = (bf16*)alloc(512 * 128 * 2);
  bf16*  h1     = (bf16*)alloc((size_t)N * 512 * 2);
  float* a_src1 = (float*)alloc((size_t)N * 8 * 4);
  float* a_dst1 = (float*)alloc((size_t)N * 8 * 4);
  float* h3     = (float*)alloc((size_t)N * 16 * 4);
  float* a_src3 = (float*)alloc((size_t)N * 4);
  float* a_dst3 = (float*)alloc((size_t)N * 4);
  float* W1pT   = (float*)alloc(128 * 16 * 4);
  float* W2pT   = (float*)alloc(512 * 16 * 4);
  float* b3p    = (float*)alloc(16 * 4);
  (void)n_in; (void)out_size;

  if (off > ws_size) {  // workspace too small: fail loudly but safely
    sentinel_kernel<<<1, 16, 0, stream>>>(out);
    return;
  }

  hipMemsetAsync(d_ws, 0, zbytes, stream);

  const int eb = (EP + 255) / 256;
  const int nb4 = (N + 3) / 4;

  cast_x_kernel<<<2048, 256, 0, stream>>>(x, xb, N * 32);
  cast_wt_kernel<<<256, 256, 0, stream>>>(g1_W, Wt);
  w1p_kernel<<<8, 256, 0, stream>>>(sk1_W, g3_W, W1pT);
  w2p_kernel<<<32, 256, 0, stream>>>(sk2_W, g3_W, W2pT);
  b3p_kernel<<<1, 16, 0, stream>>>(sk1_b, sk2_b, g3_W, b3p);

  gemm_h1_kernel<<<dim3((N + 63) / 64, 4), 256, 0, stream>>>(
      xb, Wt, g1_as, g1_ad, h1, a_src1, a_dst1, N);

  deg_kernel<<<eb, 256, 0, stream>>>(ei, deg, E, EP);
  scan_kernel<<<1, 1024, 0, stream>>>(deg, offs, N);
  scatter_kernel<<<eb, 256, 0, stream>>>(ei, offs, cursor, esrc, E, EP);

  agg1_h3_kernel<<<nb4, 256, 0, stream>>>(offs, esrc, a_src1, a_dst1, h1, g1_b, x,
                                          W1pT, W2pT, b3p, g3_as, g3_ad,
                                          h3, a_src3, a_dst3, N);

  agg3_kernel<<<nb4, 256, 0, stream>>>(offs, esrc, a_src3, a_dst3, h3, g3_b, out, N);
}